// Round 1
// baseline (3450.523 us; speedup 1.0000x reference)
//
#include <hip/hip_runtime.h>
#include <math.h>

#define SS 4096      // H*W
#define NE 4194304   // B*C*H*W

__device__ __forceinline__ float wave_max(float v) {
#pragma unroll
  for (int off = 32; off > 0; off >>= 1) v = fmaxf(v, __shfl_xor(v, off, 64));
  return v;
}
__device__ __forceinline__ float wave_sum(float v) {
#pragma unroll
  for (int off = 32; off > 0; off >>= 1) v += __shfl_xor(v, off, 64);
  return v;
}
__device__ __forceinline__ float silu_f(float y) { return y / (1.f + __expf(-y)); }

// ---------- GroupNorm stats: one block per (b,group): 8 ch * 4096 = 32768 contiguous floats
__global__ __launch_bounds__(256) void gn_stats_k(const float* __restrict__ x,
                                                  float* __restrict__ stats) {
  const float4* p = (const float4*)(x + (size_t)blockIdx.x * 32768);
  float s = 0.f, q = 0.f;
  for (int i = threadIdx.x; i < 8192; i += 256) {
    float4 v = p[i];
    s += v.x + v.y + v.z + v.w;
    q += v.x * v.x + v.y * v.y + v.z * v.z + v.w * v.w;
  }
  s = wave_sum(s); q = wave_sum(q);
  __shared__ float red[8];
  int wid = threadIdx.x >> 6;
  if ((threadIdx.x & 63) == 0) { red[wid] = s; red[wid + 4] = q; }
  __syncthreads();
  if (threadIdx.x == 0) {
    s = red[0] + red[1] + red[2] + red[3];
    q = red[4] + red[5] + red[6] + red[7];
    float m = s * (1.f / 32768.f);
    float var = q * (1.f / 32768.f) - m * m;
    stats[blockIdx.x * 2] = m;
    stats[blockIdx.x * 2 + 1] = rsqrtf(var + 1e-5f);
  }
}

// ---------- GN apply (+ optional SiLU), float4 elementwise
template <int DO_SILU>
__global__ __launch_bounds__(256) void gn_apply_k(const float* __restrict__ x,
    const float* __restrict__ stats, const float* __restrict__ sc,
    const float* __restrict__ bi, float* __restrict__ out) {
  size_t i4 = ((size_t)blockIdx.x * 256 + threadIdx.x) * 4;
  int c = (int)((i4 >> 12) & 255);
  int b = (int)(i4 >> 20);
  int sidx = (b * 32 + (c >> 3)) * 2;
  float m = stats[sidx], r = stats[sidx + 1];
  float a = sc[c] * r;
  float t = bi[c] - m * a;
  float4 v = *(const float4*)(x + i4);
  float4 o;
  o.x = v.x * a + t; o.y = v.y * a + t; o.z = v.z * a + t; o.w = v.w * a + t;
  if (DO_SILU) { o.x = silu_f(o.x); o.y = silu_f(o.y); o.z = silu_f(o.z); o.w = silu_f(o.w); }
  *(float4*)(out + i4) = o;
}

// ---------- FiLM: gb[b,j] = sum_t silu(te[b,t]) * mlp_w[j,t] + mlp_b[j]
__global__ __launch_bounds__(256) void film_k(const float* __restrict__ te,
    const float* __restrict__ w, const float* __restrict__ bi,
    float* __restrict__ gb) {
  int tid = blockIdx.x * 256 + threadIdx.x;  // 2048 threads
  int b = tid >> 9, j = tid & 511;
  const float* tp = te + b * 256;
  const float* wp = w + j * 256;
  float acc = bi[j];
  for (int t = 0; t < 256; ++t) acc += silu_f(tp[t]) * wp[t];
  gb[tid] = acc;
}

// ---------- direct 3x3 conv, SAME. MODE 0: +bias then FiLM. MODE 1: +bias +residual.
template <int MODE>
__global__ __launch_bounds__(256) void conv3x3_k(const float* __restrict__ in,
    const float* __restrict__ w, const float* __restrict__ bias,
    const float* __restrict__ gb, const float* __restrict__ resid,
    float* __restrict__ out) {
  __shared__ __align__(16) float xt[18 * 20];
  __shared__ float wl[16 * 9];
  const int tid = threadIdx.x;
  const int oc_l = tid & 15, oy_l = tid >> 4;
  const int sx = (blockIdx.x & 3) * 16, sy = (blockIdx.x >> 2) * 16;
  const int oc0 = blockIdx.y * 16;
  const int b = blockIdx.z;
  float acc[16];
#pragma unroll
  for (int i = 0; i < 16; ++i) acc[i] = 0.f;

  for (int ic = 0; ic < 256; ++ic) {
    __syncthreads();
    const float* inp = in + ((size_t)(b * 256 + ic)) * 4096;
    for (int li = tid; li < 324; li += 256) {
      int ty = li / 18, tx = li - ty * 18;
      int gy = sy + ty - 1, gx = sx + tx - 1;
      float v = 0.f;
      if ((unsigned)gy < 64u && (unsigned)gx < 64u) v = inp[gy * 64 + gx];
      xt[ty * 20 + tx] = v;
    }
    if (tid < 144) {
      int o = tid / 9, t = tid - o * 9;
      wl[tid] = w[((size_t)(oc0 + o) * 256 + ic) * 9 + t];
    }
    __syncthreads();
#pragma unroll
    for (int dy = 0; dy < 3; ++dy) {
      const float* row = &xt[(oy_l + dy) * 20];
      float r[18];
      *(float4*)&r[0]  = *(const float4*)(row + 0);
      *(float4*)&r[4]  = *(const float4*)(row + 4);
      *(float4*)&r[8]  = *(const float4*)(row + 8);
      *(float4*)&r[12] = *(const float4*)(row + 12);
      r[16] = row[16]; r[17] = row[17];
#pragma unroll
      for (int dx = 0; dx < 3; ++dx) {
        float wv = wl[oc_l * 9 + dy * 3 + dx];
#pragma unroll
        for (int ox = 0; ox < 16; ++ox) acc[ox] = fmaf(r[ox + dx], wv, acc[ox]);
      }
    }
  }
  const int oc = oc0 + oc_l;
  const float bi = bias[oc];
  float ga = 0.f, be = 0.f;
  if (MODE == 0) { ga = 1.f + gb[b * 512 + oc]; be = gb[b * 512 + 256 + oc]; }
  size_t obase = (((size_t)b * 256 + oc) * 64 + sy + oy_l) * 64 + sx;
#pragma unroll
  for (int ox = 0; ox < 16; ++ox) {
    float v = acc[ox] + bi;
    if (MODE == 0) v = ga * v + be;
    else v += resid[obase + ox];
    out[obase + ox] = v;
  }
}

// ---------- 1x1 "conv" (GEMM): qkv. out rows o0..o0+15 from in [b][c][s]
__global__ __launch_bounds__(256) void qkv_k(const float* __restrict__ n,
    const float* __restrict__ wq, float* __restrict__ q, float* __restrict__ k,
    float* __restrict__ vt) {
  __shared__ __align__(16) float wt[256 * 20];
  const int tid = threadIdx.x;
  const int s = blockIdx.x * 256 + tid;
  const int o0 = blockIdx.y * 16;
  const int b = blockIdx.z;
#pragma unroll
  for (int o = 0; o < 16; ++o) wt[tid * 20 + o] = wq[(size_t)(o0 + o) * 256 + tid];
  __syncthreads();
  const float* ip = n + (size_t)b * 256 * 4096 + s;
  float acc[16];
#pragma unroll
  for (int i = 0; i < 16; ++i) acc[i] = 0.f;
#pragma unroll 4
  for (int c = 0; c < 256; ++c) {
    float nv = ip[(size_t)c * 4096];
    const float4* wp = (const float4*)&wt[c * 20];
    float wv[16];
    *(float4*)&wv[0]  = wp[0];
    *(float4*)&wv[4]  = wp[1];
    *(float4*)&wv[8]  = wp[2];
    *(float4*)&wv[12] = wp[3];
#pragma unroll
    for (int o = 0; o < 16; ++o) acc[o] = fmaf(wv[o], nv, acc[o]);
  }
  if (o0 < 256) {
#pragma unroll
    for (int o = 0; o < 16; ++o)
      q[((size_t)(b * 256 + o0 + o)) * 4096 + s] = acc[o];
  } else if (o0 < 512) {
#pragma unroll
    for (int o = 0; o < 16; ++o)
      k[((size_t)(b * 256 + o0 - 256 + o)) * 4096 + s] = acc[o];
  } else {
    float* vp = vt + ((size_t)b * 4096 + s) * 256 + (o0 - 512);
#pragma unroll
    for (int o = 0; o < 16; o += 4)
      *(float4*)(vp + o) = *(float4*)&acc[o];
  }
}

// ---------- flash attention: 32 queries/block, 4 waves each owning 8 query rows
__global__ __launch_bounds__(256) void attn_k(const float* __restrict__ q,
    const float* __restrict__ k, const float* __restrict__ vt,
    float* __restrict__ oa) {
  __shared__ __align__(16) float qs[256 * 32];  // [c][qi], scaled by 1/16
  __shared__ __align__(16) float ps[64 * 40];   // [t][qi] pad 40
  __shared__ float al[32], ll[32];
  const int tid = threadIdx.x;
  const int b = blockIdx.y;
  const int s0 = blockIdx.x * 32;
  {
    const int qi = tid & 31, cb = tid >> 5;
    for (int r = 0; r < 32; ++r) {
      int c = r * 8 + cb;
      qs[c * 32 + qi] = q[((size_t)(b * 256 + c)) * 4096 + s0 + qi] * 0.0625f;
    }
  }
  __syncthreads();
  const int tl = tid & 63, grp = tid >> 6, qb = grp * 8;
  float m_run[8], l_run[8];
#pragma unroll
  for (int j = 0; j < 8; ++j) { m_run[j] = -1e30f; l_run[j] = 0.f; }
  float O[32];
#pragma unroll
  for (int j = 0; j < 32; ++j) O[j] = 0.f;

  const float* kb = k + (size_t)b * 256 * 4096;
  const float* vb = vt + (size_t)b * 4096 * 256;

  for (int t0 = 0; t0 < 4096; t0 += 64) {
    float sr[8];
#pragma unroll
    for (int j = 0; j < 8; ++j) sr[j] = 0.f;
    const float* kp = kb + t0 + tl;
#pragma unroll 4
    for (int c = 0; c < 256; ++c) {
      float kv = kp[(size_t)c * 4096];
      const float4* qp = (const float4*)&qs[c * 32 + qb];
      float qv[8];
      *(float4*)&qv[0] = qp[0];
      *(float4*)&qv[4] = qp[1];
#pragma unroll
      for (int j = 0; j < 8; ++j) sr[j] = fmaf(qv[j], kv, sr[j]);
    }
    float alpha[8], p[8];
#pragma unroll
    for (int j = 0; j < 8; ++j) {
      float mx = wave_max(sr[j]);
      float m_new = fmaxf(m_run[j], mx);
      alpha[j] = __expf(m_run[j] - m_new);
      p[j] = __expf(sr[j] - m_new);
      float rs = wave_sum(p[j]);
      l_run[j] = l_run[j] * alpha[j] + rs;
      m_run[j] = m_new;
      ps[tl * 40 + qb + j] = p[j];
    }
    if (tl == 0) {
#pragma unroll
      for (int j = 0; j < 8; ++j) al[qb + j] = alpha[j];
    }
    __syncthreads();
#pragma unroll
    for (int j = 0; j < 32; ++j) O[j] *= al[j];
    const float* vp = vb + (size_t)t0 * 256 + tid;
#pragma unroll 2
    for (int t = 0; t < 64; ++t) {
      float vv = vp[(size_t)t * 256];
      const float4* pp = (const float4*)&ps[t * 40];
      float pv[32];
      *(float4*)&pv[0]  = pp[0];
      *(float4*)&pv[4]  = pp[1];
      *(float4*)&pv[8]  = pp[2];
      *(float4*)&pv[12] = pp[3];
      *(float4*)&pv[16] = pp[4];
      *(float4*)&pv[20] = pp[5];
      *(float4*)&pv[24] = pp[6];
      *(float4*)&pv[28] = pp[7];
#pragma unroll
      for (int j = 0; j < 32; ++j) O[j] = fmaf(pv[j], vv, O[j]);
    }
    __syncthreads();
  }
  if (tl == 0) {
#pragma unroll
    for (int j = 0; j < 8; ++j) ll[qb + j] = l_run[j];
  }
  __syncthreads();
  float* op = oa + ((size_t)b * 256 + tid) * 4096 + s0;
#pragma unroll
  for (int j = 0; j < 32; j += 4) {
    float4 v;
    v.x = O[j] / ll[j];
    v.y = O[j + 1] / ll[j + 1];
    v.z = O[j + 2] / ll[j + 2];
    v.w = O[j + 3] / ll[j + 3];
    *(float4*)(op + j) = v;
  }
}

// ---------- out projection + bias + residual (out holds xr; RMW of own element only)
__global__ __launch_bounds__(256) void proj_k(const float* __restrict__ oa,
    const float* __restrict__ w, const float* __restrict__ ob,
    float* __restrict__ out) {
  __shared__ __align__(16) float wt[256 * 20];
  const int tid = threadIdx.x;
  const int s = blockIdx.x * 256 + tid;
  const int o0 = blockIdx.y * 16;
  const int b = blockIdx.z;
#pragma unroll
  for (int o = 0; o < 16; ++o) wt[tid * 20 + o] = w[(size_t)(o0 + o) * 256 + tid];
  __syncthreads();
  const float* ip = oa + (size_t)b * 256 * 4096 + s;
  float acc[16];
#pragma unroll
  for (int i = 0; i < 16; ++i) acc[i] = 0.f;
#pragma unroll 4
  for (int c = 0; c < 256; ++c) {
    float nv = ip[(size_t)c * 4096];
    const float4* wp = (const float4*)&wt[c * 20];
    float wv[16];
    *(float4*)&wv[0]  = wp[0];
    *(float4*)&wv[4]  = wp[1];
    *(float4*)&wv[8]  = wp[2];
    *(float4*)&wv[12] = wp[3];
#pragma unroll
    for (int o = 0; o < 16; ++o) acc[o] = fmaf(wv[o], nv, acc[o]);
  }
#pragma unroll
  for (int o = 0; o < 16; ++o) {
    size_t idx = ((size_t)(b * 256 + o0 + o)) * 4096 + s;
    out[idx] = acc[o] + ob[o0 + o] + out[idx];
  }
}

extern "C" void kernel_launch(void* const* d_in, const int* in_sizes, int n_in,
                              void* d_out, int out_size, void* d_ws, size_t ws_size,
                              hipStream_t stream) {
  const float* x       = (const float*)d_in[0];
  const float* te      = (const float*)d_in[1];
  const float* gn1_s   = (const float*)d_in[2];
  const float* gn1_b   = (const float*)d_in[3];
  const float* conv1_w = (const float*)d_in[4];
  const float* conv1_b = (const float*)d_in[5];
  const float* mlp_w   = (const float*)d_in[6];
  const float* mlp_b   = (const float*)d_in[7];
  const float* gn2_s   = (const float*)d_in[8];
  const float* gn2_b   = (const float*)d_in[9];
  const float* conv2_w = (const float*)d_in[10];
  const float* conv2_b = (const float*)d_in[11];
  const float* gnA_s   = (const float*)d_in[12];
  const float* gnA_b   = (const float*)d_in[13];
  const float* qkv_w   = (const float*)d_in[14];
  const float* out_w   = (const float*)d_in[15];
  const float* out_b   = (const float*)d_in[16];
  float* out = (float*)d_out;

  float* bufA  = (float*)d_ws;       // a1 / a2 / nA / oa (16MB)
  float* bufB  = bufA + NE;          // h1 / q
  float* bufD  = bufB + NE;          // k
  float* bufE  = bufD + NE;          // v^T [b][s][c]
  float* stats = bufE + NE;          // 3 * 256 floats
  float* gbuf  = stats + 768;        // 2048 floats

  // --- ResNet block ---
  gn_stats_k<<<128, 256, 0, stream>>>(x, stats);
  gn_apply_k<1><<<4096, 256, 0, stream>>>(x, stats, gn1_s, gn1_b, bufA);
  film_k<<<8, 256, 0, stream>>>(te, mlp_w, mlp_b, gbuf);
  conv3x3_k<0><<<dim3(16, 16, 4), 256, 0, stream>>>(bufA, conv1_w, conv1_b, gbuf,
                                                    nullptr, bufB);
  gn_stats_k<<<128, 256, 0, stream>>>(bufB, stats + 256);
  gn_apply_k<1><<<4096, 256, 0, stream>>>(bufB, stats + 256, gn2_s, gn2_b, bufA);
  conv3x3_k<1><<<dim3(16, 16, 4), 256, 0, stream>>>(bufA, conv2_w, conv2_b, nullptr,
                                                    x, out);  // out = xr
  // --- Self-attention ---
  gn_stats_k<<<128, 256, 0, stream>>>(out, stats + 512);
  gn_apply_k<0><<<4096, 256, 0, stream>>>(out, stats + 512, gnA_s, gnA_b, bufA);
  qkv_k<<<dim3(16, 48, 4), 256, 0, stream>>>(bufA, qkv_w, bufB, bufD, bufE);
  attn_k<<<dim3(128, 4), 256, 0, stream>>>(bufB, bufD, bufE, bufA);
  proj_k<<<dim3(16, 16, 4), 256, 0, stream>>>(bufA, out_w, out_b, out);
}

// Round 2
// 1442.706 us; speedup vs baseline: 2.3917x; 2.3917x over previous
//
#include <hip/hip_runtime.h>
#include <math.h>

#define SS 4096      // H*W
#define NE 4194304   // B*C*H*W

typedef __attribute__((ext_vector_type(8))) short short8;
typedef __attribute__((ext_vector_type(4))) float f32x4;

__device__ __forceinline__ float wave_sum(float v) {
#pragma unroll
  for (int off = 32; off > 0; off >>= 1) v += __shfl_xor(v, off, 64);
  return v;
}
__device__ __forceinline__ float silu_f(float y) { return y / (1.f + __expf(-y)); }

__device__ __forceinline__ unsigned short to_bf(float x) {
  union { float f; unsigned u; } v; v.f = x;
  unsigned r = v.u + 0x7FFFu + ((v.u >> 16) & 1u);
  return (unsigned short)(r >> 16);
}

// ---------- GroupNorm stats: one block per (b,group): 8 ch * 4096 contiguous floats
__global__ __launch_bounds__(256) void gn_stats_k(const float* __restrict__ x,
                                                  float* __restrict__ stats) {
  const float4* p = (const float4*)(x + (size_t)blockIdx.x * 32768);
  float s = 0.f, q = 0.f;
  for (int i = threadIdx.x; i < 8192; i += 256) {
    float4 v = p[i];
    s += v.x + v.y + v.z + v.w;
    q += v.x * v.x + v.y * v.y + v.z * v.z + v.w * v.w;
  }
  s = wave_sum(s); q = wave_sum(q);
  __shared__ float red[8];
  int wid = threadIdx.x >> 6;
  if ((threadIdx.x & 63) == 0) { red[wid] = s; red[wid + 4] = q; }
  __syncthreads();
  if (threadIdx.x == 0) {
    s = red[0] + red[1] + red[2] + red[3];
    q = red[4] + red[5] + red[6] + red[7];
    float m = s * (1.f / 32768.f);
    float var = q * (1.f / 32768.f) - m * m;
    stats[blockIdx.x * 2] = m;
    stats[blockIdx.x * 2 + 1] = rsqrtf(var + 1e-5f);
  }
}

// ---------- GN apply (+ optional SiLU)
template <int DO_SILU>
__global__ __launch_bounds__(256) void gn_apply_k(const float* __restrict__ x,
    const float* __restrict__ stats, const float* __restrict__ sc,
    const float* __restrict__ bi, float* __restrict__ out) {
  size_t i4 = ((size_t)blockIdx.x * 256 + threadIdx.x) * 4;
  int c = (int)((i4 >> 12) & 255);
  int b = (int)(i4 >> 20);
  int sidx = (b * 32 + (c >> 3)) * 2;
  float m = stats[sidx], r = stats[sidx + 1];
  float a = sc[c] * r;
  float t = bi[c] - m * a;
  float4 v = *(const float4*)(x + i4);
  float4 o;
  o.x = v.x * a + t; o.y = v.y * a + t; o.z = v.z * a + t; o.w = v.w * a + t;
  if (DO_SILU) { o.x = silu_f(o.x); o.y = silu_f(o.y); o.z = silu_f(o.z); o.w = silu_f(o.w); }
  *(float4*)(out + i4) = o;
}

// ---------- FiLM MLP
__global__ __launch_bounds__(256) void film_k(const float* __restrict__ te,
    const float* __restrict__ w, const float* __restrict__ bi,
    float* __restrict__ gb) {
  int tid = blockIdx.x * 256 + threadIdx.x;  // 2048 threads
  int b = tid >> 9, j = tid & 511;
  const float* tp = te + b * 256;
  const float* wp = w + j * 256;
  float acc = bi[j];
  for (int t = 0; t < 256; ++t) acc += silu_f(tp[t]) * wp[t];
  gb[tid] = acc;
}

// ---------- direct 3x3 conv, SAME. MODE 0: +bias then FiLM. MODE 1: +bias +residual.
template <int MODE>
__global__ __launch_bounds__(256) void conv3x3_k(const float* __restrict__ in,
    const float* __restrict__ w, const float* __restrict__ bias,
    const float* __restrict__ gb, const float* __restrict__ resid,
    float* __restrict__ out) {
  __shared__ __align__(16) float xt[18 * 20];
  __shared__ float wl[16 * 9];
  const int tid = threadIdx.x;
  const int oc_l = tid & 15, oy_l = tid >> 4;
  const int sx = (blockIdx.x & 3) * 16, sy = (blockIdx.x >> 2) * 16;
  const int oc0 = blockIdx.y * 16;
  const int b = blockIdx.z;
  float acc[16];
#pragma unroll
  for (int i = 0; i < 16; ++i) acc[i] = 0.f;

  for (int ic = 0; ic < 256; ++ic) {
    __syncthreads();
    const float* inp = in + ((size_t)(b * 256 + ic)) * 4096;
    for (int li = tid; li < 324; li += 256) {
      int ty = li / 18, tx = li - ty * 18;
      int gy = sy + ty - 1, gx = sx + tx - 1;
      float v = 0.f;
      if ((unsigned)gy < 64u && (unsigned)gx < 64u) v = inp[gy * 64 + gx];
      xt[ty * 20 + tx] = v;
    }
    if (tid < 144) {
      int o = tid / 9, t = tid - o * 9;
      wl[tid] = w[((size_t)(oc0 + o) * 256 + ic) * 9 + t];
    }
    __syncthreads();
#pragma unroll
    for (int dy = 0; dy < 3; ++dy) {
      const float* row = &xt[(oy_l + dy) * 20];
      float r[18];
      *(float4*)&r[0]  = *(const float4*)(row + 0);
      *(float4*)&r[4]  = *(const float4*)(row + 4);
      *(float4*)&r[8]  = *(const float4*)(row + 8);
      *(float4*)&r[12] = *(const float4*)(row + 12);
      r[16] = row[16]; r[17] = row[17];
#pragma unroll
      for (int dx = 0; dx < 3; ++dx) {
        float wv = wl[oc_l * 9 + dy * 3 + dx];
#pragma unroll
        for (int ox = 0; ox < 16; ++ox) acc[ox] = fmaf(r[ox + dx], wv, acc[ox]);
      }
    }
  }
  const int oc = oc0 + oc_l;
  const float bi = bias[oc];
  float ga = 0.f, be = 0.f;
  if (MODE == 0) { ga = 1.f + gb[b * 512 + oc]; be = gb[b * 512 + 256 + oc]; }
  size_t obase = (((size_t)b * 256 + oc) * 64 + sy + oy_l) * 64 + sx;
#pragma unroll
  for (int ox = 0; ox < 16; ++ox) {
    float v = acc[ox] + bi;
    if (MODE == 0) v = ga * v + be;
    else v += resid[obase + ox];
    out[obase + ox] = v;
  }
}

// ---------- 1x1 qkv GEMM: fp32 in, bf16 out in MFMA-friendly layouts.
// q,k -> [b][s][256] bf16 (q pre-scaled by 1/16); v -> [b][c][4096] bf16.
__global__ __launch_bounds__(256) void qkv_k(const float* __restrict__ n,
    const float* __restrict__ wq, short* __restrict__ q, short* __restrict__ k,
    short* __restrict__ v) {
  __shared__ __align__(16) float wt[256 * 20];
  const int tid = threadIdx.x;
  const int s = blockIdx.x * 256 + tid;
  const int o0 = blockIdx.y * 16;
  const int b = blockIdx.z;
#pragma unroll
  for (int o = 0; o < 16; ++o) wt[tid * 20 + o] = wq[(size_t)(o0 + o) * 256 + tid];
  __syncthreads();
  const float* ip = n + (size_t)b * 256 * 4096 + s;
  float acc[16];
#pragma unroll
  for (int i = 0; i < 16; ++i) acc[i] = 0.f;
#pragma unroll 4
  for (int c = 0; c < 256; ++c) {
    float nv = ip[(size_t)c * 4096];
    const float4* wp = (const float4*)&wt[c * 20];
    float wv[16];
    *(float4*)&wv[0]  = wp[0];
    *(float4*)&wv[4]  = wp[1];
    *(float4*)&wv[8]  = wp[2];
    *(float4*)&wv[12] = wp[3];
#pragma unroll
    for (int o = 0; o < 16; ++o) acc[o] = fmaf(wv[o], nv, acc[o]);
  }
  if (o0 < 256) {
    union { short8 v8[2]; unsigned short s16[16]; } u;
#pragma unroll
    for (int o = 0; o < 16; ++o) u.s16[o] = to_bf(acc[o] * 0.0625f);
    short* qp = q + ((size_t)(b * 4096 + s)) * 256 + o0;
    *(short8*)qp = u.v8[0];
    *(short8*)(qp + 8) = u.v8[1];
  } else if (o0 < 512) {
    union { short8 v8[2]; unsigned short s16[16]; } u;
#pragma unroll
    for (int o = 0; o < 16; ++o) u.s16[o] = to_bf(acc[o]);
    short* kp = k + ((size_t)(b * 4096 + s)) * 256 + (o0 - 256);
    *(short8*)kp = u.v8[0];
    *(short8*)(kp + 8) = u.v8[1];
  } else {
#pragma unroll
    for (int o = 0; o < 16; ++o)
      v[((size_t)(b * 256 + o0 - 512 + o)) * 4096 + s] = (short)to_bf(acc[o]);
  }
}

// ---------- MFMA flash attention.
// 4 waves x 16 query rows = 64 queries/block; 32-key tiles; K/V staged in LDS
// with pad (2-way max bank aliasing = free); Q frags in regs; P via per-wave LDS.
__global__ __launch_bounds__(256, 1) void attn_k(const short* __restrict__ qb,
    const short* __restrict__ kb, const short* __restrict__ vb,
    float* __restrict__ oa) {
  __shared__ short kls[32 * 264];   // K-tile [t][c], row pad +8
  __shared__ short vls[256 * 40];   // V-tile [c][t], row pad +8
  __shared__ short pls[4 * 16 * 40];// per-wave P [m][t], row pad +8
  const int tid = threadIdx.x;
  const int b = blockIdx.y;
  const int s0 = blockIdx.x * 64;
  const int wv = tid >> 6, lane = tid & 63, ln = lane & 15, qd = lane >> 4;

  // Q fragments: A[m=ln][k=qd*8+j], k-step ks covers c = ks*32 + qd*8 + j
  short8 qf[8];
  {
    const short* qp = qb + ((size_t)(b * 4096 + s0 + wv * 16 + ln)) * 256 + qd * 8;
#pragma unroll
    for (int ks = 0; ks < 8; ++ks) qf[ks] = *(const short8*)(qp + ks * 32);
  }
  const f32x4 z4 = {0.f, 0.f, 0.f, 0.f};
  f32x4 O[16];
#pragma unroll
  for (int i = 0; i < 16; ++i) O[i] = z4;
  float m_run[4] = {-3e38f, -3e38f, -3e38f, -3e38f};
  float l_run[4] = {0.f, 0.f, 0.f, 0.f};

  const int krow = tid >> 3, kch = tid & 7;  // K staging: 32 rows x 32 chunks
  const int vcol = tid >> 2, vch = tid & 3;  // V staging: 256 rows x 4 chunks
  const short* kbb = kb + ((size_t)b * 4096) * 256;
  const short* vbb = vb + ((size_t)b * 256) * 4096;

  short8 kreg[4], vreg[4];
#pragma unroll
  for (int i = 0; i < 4; ++i) {
    kreg[i] = *(const short8*)(kbb + (size_t)krow * 256 + (kch + i * 8) * 8);
    vreg[i] = *(const short8*)(vbb + (size_t)(vcol)*4096 + (size_t)i * 64 * 4096 + vch * 8);
  }
#pragma unroll
  for (int i = 0; i < 4; ++i) {
    *(short8*)&kls[krow * 264 + (kch + i * 8) * 8] = kreg[i];
    *(short8*)&vls[(vcol + i * 64) * 40 + vch * 8] = vreg[i];
  }
  __syncthreads();

  for (int t0 = 0; t0 < 4096; t0 += 32) {
    const int t1 = t0 + 32;
    if (t1 < 4096) {
#pragma unroll
      for (int i = 0; i < 4; ++i) {
        kreg[i] = *(const short8*)(kbb + (size_t)(t1 + krow) * 256 + (kch + i * 8) * 8);
        vreg[i] = *(const short8*)(vbb + ((size_t)(vcol + i * 64)) * 4096 + t1 + vch * 8);
      }
    }
    // S = Q K^T  (two 16-col tiles of the 32 keys)
    f32x4 S0 = z4, S1 = z4;
#pragma unroll
    for (int ks = 0; ks < 8; ++ks) {
      short8 k0 = *(const short8*)&kls[ln * 264 + ks * 32 + qd * 8];
      short8 k1 = *(const short8*)&kls[(16 + ln) * 264 + ks * 32 + qd * 8];
      S0 = __builtin_amdgcn_mfma_f32_16x16x32_bf16(qf[ks], k0, S0, 0, 0, 0);
      S1 = __builtin_amdgcn_mfma_f32_16x16x32_bf16(qf[ks], k1, S1, 0, 0, 0);
    }
    // online softmax (rows live in 16-lane quads: row = qd*4 + r)
    float al[4];
#pragma unroll
    for (int r = 0; r < 4; ++r) {
      float sm = fmaxf(S0[r], S1[r]);
      sm = fmaxf(sm, __shfl_xor(sm, 1, 16));
      sm = fmaxf(sm, __shfl_xor(sm, 2, 16));
      sm = fmaxf(sm, __shfl_xor(sm, 4, 16));
      sm = fmaxf(sm, __shfl_xor(sm, 8, 16));
      float mn = fmaxf(m_run[r], sm);
      al[r] = __expf(m_run[r] - mn);
      float p0 = __expf(S0[r] - mn), p1 = __expf(S1[r] - mn);
      float rs = p0 + p1;
      rs += __shfl_xor(rs, 1, 16);
      rs += __shfl_xor(rs, 2, 16);
      rs += __shfl_xor(rs, 4, 16);
      rs += __shfl_xor(rs, 8, 16);
      l_run[r] = l_run[r] * al[r] + rs;
      m_run[r] = mn;
      pls[wv * 640 + (qd * 4 + r) * 40 + ln] = (short)to_bf(p0);
      pls[wv * 640 + (qd * 4 + r) * 40 + 16 + ln] = (short)to_bf(p1);
    }
#pragma unroll
    for (int cn = 0; cn < 16; ++cn) {
#pragma unroll
      for (int r = 0; r < 4; ++r) O[cn][r] *= al[r];
    }
    // PV: A = P (own wave's LDS region), B = V-tile
    short8 pf = *(const short8*)&pls[wv * 640 + ln * 40 + qd * 8];
#pragma unroll
    for (int cn = 0; cn < 16; ++cn) {
      short8 vf = *(const short8*)&vls[(cn * 16 + ln) * 40 + qd * 8];
      O[cn] = __builtin_amdgcn_mfma_f32_16x16x32_bf16(pf, vf, O[cn], 0, 0, 0);
    }
    __syncthreads();
    if (t1 < 4096) {
#pragma unroll
      for (int i = 0; i < 4; ++i) {
        *(short8*)&kls[krow * 264 + (kch + i * 8) * 8] = kreg[i];
        *(short8*)&vls[(vcol + i * 64) * 40 + vch * 8] = vreg[i];
      }
    }
    __syncthreads();
  }
  float inv[4];
#pragma unroll
  for (int r = 0; r < 4; ++r) inv[r] = 1.f / l_run[r];
  float* op = oa + ((size_t)(b * 4096 + s0 + wv * 16 + qd * 4)) * 256 + ln;
#pragma unroll
  for (int cn = 0; cn < 16; ++cn) {
#pragma unroll
    for (int r = 0; r < 4; ++r)
      op[(size_t)r * 256 + cn * 16] = O[cn][r] * inv[r];
  }
}

// ---------- out projection + bias + residual; oa is [b][s][c] fp32
__global__ __launch_bounds__(256) void proj_k(const float* __restrict__ oa,
    const float* __restrict__ w, const float* __restrict__ ob,
    float* __restrict__ out) {
  __shared__ __align__(16) float wt[256 * 20];
  const int tid = threadIdx.x;
  const int s = blockIdx.x * 256 + tid;
  const int o0 = blockIdx.y * 16;
  const int b = blockIdx.z;
#pragma unroll
  for (int o = 0; o < 16; ++o) wt[tid * 20 + o] = w[(size_t)(o0 + o) * 256 + tid];
  __syncthreads();
  const float4* ip = (const float4*)(oa + ((size_t)(b * 4096) + s) * 256);
  float acc[16];
#pragma unroll
  for (int i = 0; i < 16; ++i) acc[i] = 0.f;
  for (int c4 = 0; c4 < 64; ++c4) {
    float4 nv = ip[c4];
    float xs[4] = {nv.x, nv.y, nv.z, nv.w};
#pragma unroll
    for (int cc = 0; cc < 4; ++cc) {
      const float4* wp = (const float4*)&wt[(c4 * 4 + cc) * 20];
      float wv[16];
      *(float4*)&wv[0]  = wp[0];
      *(float4*)&wv[4]  = wp[1];
      *(float4*)&wv[8]  = wp[2];
      *(float4*)&wv[12] = wp[3];
#pragma unroll
      for (int o = 0; o < 16; ++o) acc[o] = fmaf(wv[o], xs[cc], acc[o]);
    }
  }
#pragma unroll
  for (int o = 0; o < 16; ++o) {
    size_t idx = ((size_t)(b * 256 + o0 + o)) * 4096 + s;
    out[idx] = acc[o] + ob[o0 + o] + out[idx];
  }
}

extern "C" void kernel_launch(void* const* d_in, const int* in_sizes, int n_in,
                              void* d_out, int out_size, void* d_ws, size_t ws_size,
                              hipStream_t stream) {
  const float* x       = (const float*)d_in[0];
  const float* te      = (const float*)d_in[1];
  const float* gn1_s   = (const float*)d_in[2];
  const float* gn1_b   = (const float*)d_in[3];
  const float* conv1_w = (const float*)d_in[4];
  const float* conv1_b = (const float*)d_in[5];
  const float* mlp_w   = (const float*)d_in[6];
  const float* mlp_b   = (const float*)d_in[7];
  const float* gn2_s   = (const float*)d_in[8];
  const float* gn2_b   = (const float*)d_in[9];
  const float* conv2_w = (const float*)d_in[10];
  const float* conv2_b = (const float*)d_in[11];
  const float* gnA_s   = (const float*)d_in[12];
  const float* gnA_b   = (const float*)d_in[13];
  const float* qkv_w   = (const float*)d_in[14];
  const float* out_w   = (const float*)d_in[15];
  const float* out_b   = (const float*)d_in[16];
  float* out = (float*)d_out;

  float* bufA  = (float*)d_ws;       // a1 / a2 / nA / oa (16MB)
  float* bufB  = bufA + NE;          // h1 (16MB)
  short* qb    = (short*)(bufB + NE);// q bf16 [b][s][c] (8MB)
  short* kb    = qb + NE;            // k bf16 [b][s][c] (8MB)
  short* vb    = kb + NE;            // v bf16 [b][c][s] (8MB)
  float* stats = (float*)(vb + NE);  // 3 * 256 floats
  float* gbuf  = stats + 768;        // 2048 floats

  // --- ResNet block ---
  gn_stats_k<<<128, 256, 0, stream>>>(x, stats);
  gn_apply_k<1><<<4096, 256, 0, stream>>>(x, stats, gn1_s, gn1_b, bufA);
  film_k<<<8, 256, 0, stream>>>(te, mlp_w, mlp_b, gbuf);
  conv3x3_k<0><<<dim3(16, 16, 4), 256, 0, stream>>>(bufA, conv1_w, conv1_b, gbuf,
                                                    nullptr, bufB);
  gn_stats_k<<<128, 256, 0, stream>>>(bufB, stats + 256);
  gn_apply_k<1><<<4096, 256, 0, stream>>>(bufB, stats + 256, gn2_s, gn2_b, bufA);
  conv3x3_k<1><<<dim3(16, 16, 4), 256, 0, stream>>>(bufA, conv2_w, conv2_b, nullptr,
                                                    x, out);  // out = xr
  // --- Self-attention ---
  gn_stats_k<<<128, 256, 0, stream>>>(out, stats + 512);
  gn_apply_k<0><<<4096, 256, 0, stream>>>(out, stats + 512, gnA_s, gnA_b, bufA);
  qkv_k<<<dim3(16, 48, 4), 256, 0, stream>>>(bufA, qkv_w, qb, kb, vb);
  attn_k<<<dim3(64, 4), 256, 0, stream>>>(qb, kb, vb, bufA);
  proj_k<<<dim3(16, 16, 4), 256, 0, stream>>>(bufA, out_w, out_b, out);
}

// Round 3
// 691.829 us; speedup vs baseline: 4.9875x; 2.0853x over previous
//
#include <hip/hip_runtime.h>
#include <math.h>

#define SS 4096      // H*W
#define NE 4194304   // B*C*H*W

typedef __attribute__((ext_vector_type(8))) short short8;
typedef __attribute__((ext_vector_type(4))) short short4v;
typedef __attribute__((ext_vector_type(4))) float f32x4;
typedef __attribute__((ext_vector_type(16))) float f32x16;

__device__ __forceinline__ float wave_sum(float v) {
#pragma unroll
  for (int off = 32; off > 0; off >>= 1) v += __shfl_xor(v, off, 64);
  return v;
}
__device__ __forceinline__ float silu_f(float y) { return y / (1.f + __expf(-y)); }

__device__ __forceinline__ unsigned short to_bf(float x) {
  union { float f; unsigned u; } v; v.f = x;
  unsigned r = v.u + 0x7FFFu + ((v.u >> 16) & 1u);
  return (unsigned short)(r >> 16);
}

// ---------- GroupNorm stats: one block per (b,group): 8 ch * 4096 contiguous floats
__global__ __launch_bounds__(256) void gn_stats_k(const float* __restrict__ x,
                                                  float* __restrict__ stats) {
  const float4* p = (const float4*)(x + (size_t)blockIdx.x * 32768);
  float s = 0.f, q = 0.f;
  for (int i = threadIdx.x; i < 8192; i += 256) {
    float4 v = p[i];
    s += v.x + v.y + v.z + v.w;
    q += v.x * v.x + v.y * v.y + v.z * v.z + v.w * v.w;
  }
  s = wave_sum(s); q = wave_sum(q);
  __shared__ float red[8];
  int wid = threadIdx.x >> 6;
  if ((threadIdx.x & 63) == 0) { red[wid] = s; red[wid + 4] = q; }
  __syncthreads();
  if (threadIdx.x == 0) {
    s = red[0] + red[1] + red[2] + red[3];
    q = red[4] + red[5] + red[6] + red[7];
    float m = s * (1.f / 32768.f);
    float var = q * (1.f / 32768.f) - m * m;
    stats[blockIdx.x * 2] = m;
    stats[blockIdx.x * 2 + 1] = rsqrtf(var + 1e-5f);
  }
}

// ---------- GN apply, fp32 out (attention path)
__global__ __launch_bounds__(256) void gn_apply_k(const float* __restrict__ x,
    const float* __restrict__ stats, const float* __restrict__ sc,
    const float* __restrict__ bi, float* __restrict__ out) {
  size_t i4 = ((size_t)blockIdx.x * 256 + threadIdx.x) * 4;
  int c = (int)((i4 >> 12) & 255);
  int b = (int)(i4 >> 20);
  int sidx = (b * 32 + (c >> 3)) * 2;
  float m = stats[sidx], r = stats[sidx + 1];
  float a = sc[c] * r;
  float t = bi[c] - m * a;
  float4 v = *(const float4*)(x + i4);
  float4 o;
  o.x = v.x * a + t; o.y = v.y * a + t; o.z = v.z * a + t; o.w = v.w * a + t;
  *(float4*)(out + i4) = o;
}

// ---------- fused GN + SiLU + bf16 + transpose -> G[b][s][c]  (conv input)
__global__ __launch_bounds__(256) void gn_silu_t_k(const float* __restrict__ x,
    const float* __restrict__ stats, const float* __restrict__ sc,
    const float* __restrict__ bi, short* __restrict__ G) {
  __shared__ short T[64][72];
  const int tid = threadIdx.x;
  const int st = blockIdx.x & 63;           // 64 s-tiles
  const int ct = (blockIdx.x >> 6) & 3;     // 4 c-tiles
  const int b = blockIdx.x >> 8;
  const int s0 = st * 64, c0 = ct * 64;
#pragma unroll
  for (int r = 0; r < 4; ++r) {
    int idx = r * 256 + tid;
    int c_l = idx >> 4, s4 = idx & 15;
    int c = c0 + c_l;
    int sidx = (b * 32 + (c >> 3)) * 2;
    float m = stats[sidx], rs = stats[sidx + 1];
    float a = sc[c] * rs;
    float t = bi[c] - m * a;
    float4 v = *(const float4*)(x + ((size_t)(b * 256 + c)) * 4096 + s0 + s4 * 4);
    T[s4 * 4 + 0][c_l] = (short)to_bf(silu_f(v.x * a + t));
    T[s4 * 4 + 1][c_l] = (short)to_bf(silu_f(v.y * a + t));
    T[s4 * 4 + 2][c_l] = (short)to_bf(silu_f(v.z * a + t));
    T[s4 * 4 + 3][c_l] = (short)to_bf(silu_f(v.w * a + t));
  }
  __syncthreads();
#pragma unroll
  for (int r = 0; r < 2; ++r) {
    int idx = r * 256 + tid;
    int s_l = idx >> 3, cg = idx & 7;
    *(short8*)(G + ((size_t)(b * 4096 + s0 + s_l)) * 256 + c0 + cg * 8) =
        *(const short8*)&T[s_l][cg * 8];
  }
}

// ---------- weight prep: W[oc][ic][3][3] fp32 -> Wt[t][oc][ic] bf16
__global__ __launch_bounds__(256) void wprep_k(const float* __restrict__ w,
                                               short* __restrict__ wt) {
  __shared__ short L[9][256];
  const int oc = blockIdx.x;
  const int tid = threadIdx.x;
  const float* wp = w + (size_t)oc * 2304;
  for (int i = tid; i < 2304; i += 256) {
    int ic = i / 9, t = i - ic * 9;
    L[t][ic] = (short)to_bf(wp[i]);
  }
  __syncthreads();
  for (int i = tid; i < 2304; i += 256) {
    int t = i >> 8, ic = i & 255;
    wt[((size_t)(t * 256 + oc)) * 256 + ic] = L[t][ic];
  }
}

__device__ __forceinline__ short8 ld2x4(const short* p) {
  short4v lo = *(const short4v*)p;
  short4v hi = *(const short4v*)(p + 4);
  short8 r;
  r[0] = lo[0]; r[1] = lo[1]; r[2] = lo[2]; r[3] = lo[3];
  r[4] = hi[0]; r[5] = hi[1]; r[6] = hi[2]; r[7] = hi[3];
  return r;
}

// ---------- MFMA 3x3 conv (9-tap implicit GEMM), bf16 in, fp32 out [b][c][s].
// Block: 64 oc x 4 image rows (256 sp); wave w owns row oy+w, 64x64 tile.
// MODE 0: +bias then FiLM.  MODE 1: +bias +residual.
template <int MODE>
__global__ __launch_bounds__(256, 1) void conv_mfma_k(
    const short* __restrict__ G,     // [b][4096][256] bf16
    const short* __restrict__ Wt,    // [9][256][256] bf16
    const float* __restrict__ bias,
    const float* __restrict__ gb,    // FiLM [b][512]
    const float* __restrict__ resid,
    float* __restrict__ out) {
  __shared__ __align__(16) short Xs[6][66][36];  // pad 36: 2-way banks, b64 reads
  __shared__ __align__(16) short Ws[9][64][32];
  const int tid = threadIdx.x;
  const int oc0 = (blockIdx.x & 3) * 64;
  const int oy = ((blockIdx.x >> 2) & 15) * 4;
  const int b = blockIdx.x >> 6;
  const int wv = tid >> 6, lane = tid & 63;
  const int ln = lane & 31, hf = lane >> 5;

  f32x16 O00 = {}, O01 = {}, O10 = {}, O11 = {};

  for (int ic0 = 0; ic0 < 256; ic0 += 32) {
    __syncthreads();
    // stage X: 6 rows x 66 cols x 4 granules(8 ic)
    for (int i = tid; i < 1584; i += 256) {
      int r = i / 264;
      int rem = i - r * 264;
      int col = rem >> 2, g = rem & 3;
      int gy = oy + r - 1, gx = col - 1;
      short4v lo = {0, 0, 0, 0}, hi = {0, 0, 0, 0};
      if ((unsigned)gy < 64u && (unsigned)gx < 64u) {
        const short* gp = G + ((size_t)(b * 4096 + gy * 64 + gx)) * 256 + ic0 + g * 8;
        lo = *(const short4v*)gp;
        hi = *(const short4v*)(gp + 4);
      }
      *(short4v*)&Xs[r][col][g * 8] = lo;
      *(short4v*)&Xs[r][col][g * 8 + 4] = hi;
    }
    // stage W: 9 taps x 64 oc x 4 granules
    for (int i = tid; i < 2304; i += 256) {
      int t = i >> 8;
      int rem = i & 255;
      int o = rem >> 2, g = rem & 3;
      *(short8*)&Ws[t][o][g * 8] =
          *(const short8*)(Wt + ((size_t)(t * 256 + oc0 + o)) * 256 + ic0 + g * 8);
    }
    __syncthreads();
    for (int t = 0; t < 9; ++t) {
      const int dy = t / 3, dx = t - dy * 3;
      const short* xrow = &Xs[wv + dy][0][0];
#pragma unroll
      for (int ks = 0; ks < 2; ++ks) {
        short8 a0 = *(const short8*)&Ws[t][ln][ks * 16 + hf * 8];
        short8 a1 = *(const short8*)&Ws[t][32 + ln][ks * 16 + hf * 8];
        short8 b0 = ld2x4(xrow + (ln + dx) * 36 + ks * 16 + hf * 8);
        short8 b1 = ld2x4(xrow + (32 + ln + dx) * 36 + ks * 16 + hf * 8);
        O00 = __builtin_amdgcn_mfma_f32_32x32x16_bf16(a0, b0, O00, 0, 0, 0);
        O01 = __builtin_amdgcn_mfma_f32_32x32x16_bf16(a0, b1, O01, 0, 0, 0);
        O10 = __builtin_amdgcn_mfma_f32_32x32x16_bf16(a1, b0, O10, 0, 0, 0);
        O11 = __builtin_amdgcn_mfma_f32_32x32x16_bf16(a1, b1, O11, 0, 0, 0);
      }
    }
  }
  // epilogue: C row = (i&3) + 8*(i>>2) + 4*hf (oc within 32), col = ln (sp)
  const int srow = (oy + wv) * 64;
#pragma unroll
  for (int os = 0; os < 2; ++os) {
    const f32x16* Oa = os ? &O10 : &O00;
    const f32x16* Ob = os ? &O11 : &O01;
#pragma unroll
    for (int i = 0; i < 16; ++i) {
      int oc = oc0 + os * 32 + (i & 3) + 8 * (i >> 2) + 4 * hf;
      float bi = bias[oc];
      size_t base = ((size_t)(b * 256 + oc)) * 4096 + srow;
      float v0 = (*Oa)[i] + bi, v1 = (*Ob)[i] + bi;
      if (MODE == 0) {
        float ga = 1.f + gb[b * 512 + oc], be = gb[b * 512 + 256 + oc];
        v0 = ga * v0 + be;
        v1 = ga * v1 + be;
      } else {
        v0 += resid[base + ln];
        v1 += resid[base + 32 + ln];
      }
      out[base + ln] = v0;
      out[base + 32 + ln] = v1;
    }
  }
}

// ---------- FiLM MLP
__global__ __launch_bounds__(256) void film_k(const float* __restrict__ te,
    const float* __restrict__ w, const float* __restrict__ bi,
    float* __restrict__ gb) {
  int tid = blockIdx.x * 256 + threadIdx.x;  // 2048 threads
  int b = tid >> 9, j = tid & 511;
  const float* tp = te + b * 256;
  const float* wp = w + j * 256;
  float acc = bi[j];
  for (int t = 0; t < 256; ++t) acc += silu_f(tp[t]) * wp[t];
  gb[tid] = acc;
}

// ---------- 1x1 qkv GEMM: fp32 in, bf16 out in MFMA-friendly layouts.
__global__ __launch_bounds__(256) void qkv_k(const float* __restrict__ n,
    const float* __restrict__ wq, short* __restrict__ q, short* __restrict__ k,
    short* __restrict__ v) {
  __shared__ __align__(16) float wt[256 * 20];
  const int tid = threadIdx.x;
  const int s = blockIdx.x * 256 + tid;
  const int o0 = blockIdx.y * 16;
  const int b = blockIdx.z;
#pragma unroll
  for (int o = 0; o < 16; ++o) wt[tid * 20 + o] = wq[(size_t)(o0 + o) * 256 + tid];
  __syncthreads();
  const float* ip = n + (size_t)b * 256 * 4096 + s;
  float acc[16];
#pragma unroll
  for (int i = 0; i < 16; ++i) acc[i] = 0.f;
#pragma unroll 4
  for (int c = 0; c < 256; ++c) {
    float nv = ip[(size_t)c * 4096];
    const float4* wp = (const float4*)&wt[c * 20];
    float wv[16];
    *(float4*)&wv[0]  = wp[0];
    *(float4*)&wv[4]  = wp[1];
    *(float4*)&wv[8]  = wp[2];
    *(float4*)&wv[12] = wp[3];
#pragma unroll
    for (int o = 0; o < 16; ++o) acc[o] = fmaf(wv[o], nv, acc[o]);
  }
  if (o0 < 256) {
    union { short8 v8[2]; unsigned short s16[16]; } u;
#pragma unroll
    for (int o = 0; o < 16; ++o) u.s16[o] = to_bf(acc[o] * 0.0625f);
    short* qp = q + ((size_t)(b * 4096 + s)) * 256 + o0;
    *(short8*)qp = u.v8[0];
    *(short8*)(qp + 8) = u.v8[1];
  } else if (o0 < 512) {
    union { short8 v8[2]; unsigned short s16[16]; } u;
#pragma unroll
    for (int o = 0; o < 16; ++o) u.s16[o] = to_bf(acc[o]);
    short* kp = k + ((size_t)(b * 4096 + s)) * 256 + (o0 - 256);
    *(short8*)kp = u.v8[0];
    *(short8*)(kp + 8) = u.v8[1];
  } else {
#pragma unroll
    for (int o = 0; o < 16; ++o)
      v[((size_t)(b * 256 + o0 - 512 + o)) * 4096 + s] = (short)to_bf(acc[o]);
  }
}

// ---------- MFMA flash attention (unchanged from R1)
__global__ __launch_bounds__(256, 1) void attn_k(const short* __restrict__ qb,
    const short* __restrict__ kb, const short* __restrict__ vb,
    float* __restrict__ oa) {
  __shared__ short kls[32 * 264];
  __shared__ short vls[256 * 40];
  __shared__ short pls[4 * 16 * 40];
  const int tid = threadIdx.x;
  const int b = blockIdx.y;
  const int s0 = blockIdx.x * 64;
  const int wv = tid >> 6, lane = tid & 63, ln = lane & 15, qd = lane >> 4;

  short8 qf[8];
  {
    const short* qp = qb + ((size_t)(b * 4096 + s0 + wv * 16 + ln)) * 256 + qd * 8;
#pragma unroll
    for (int ks = 0; ks < 8; ++ks) qf[ks] = *(const short8*)(qp + ks * 32);
  }
  const f32x4 z4 = {0.f, 0.f, 0.f, 0.f};
  f32x4 O[16];
#pragma unroll
  for (int i = 0; i < 16; ++i) O[i] = z4;
  float m_run[4] = {-3e38f, -3e38f, -3e38f, -3e38f};
  float l_run[4] = {0.f, 0.f, 0.f, 0.f};

  const int krow = tid >> 3, kch = tid & 7;
  const int vcol = tid >> 2, vch = tid & 3;
  const short* kbb = kb + ((size_t)b * 4096) * 256;
  const short* vbb = vb + ((size_t)b * 256) * 4096;

  short8 kreg[4], vreg[4];
#pragma unroll
  for (int i = 0; i < 4; ++i) {
    kreg[i] = *(const short8*)(kbb + (size_t)krow * 256 + (kch + i * 8) * 8);
    vreg[i] = *(const short8*)(vbb + (size_t)(vcol)*4096 + (size_t)i * 64 * 4096 + vch * 8);
  }
#pragma unroll
  for (int i = 0; i < 4; ++i) {
    *(short8*)&kls[krow * 264 + (kch + i * 8) * 8] = kreg[i];
    *(short8*)&vls[(vcol + i * 64) * 40 + vch * 8] = vreg[i];
  }
  __syncthreads();

  for (int t0 = 0; t0 < 4096; t0 += 32) {
    const int t1 = t0 + 32;
    if (t1 < 4096) {
#pragma unroll
      for (int i = 0; i < 4; ++i) {
        kreg[i] = *(const short8*)(kbb + (size_t)(t1 + krow) * 256 + (kch + i * 8) * 8);
        vreg[i] = *(const short8*)(vbb + ((size_t)(vcol + i * 64)) * 4096 + t1 + vch * 8);
      }
    }
    f32x4 S0 = z4, S1 = z4;
#pragma unroll
    for (int ks = 0; ks < 8; ++ks) {
      short8 k0 = *(const short8*)&kls[ln * 264 + ks * 32 + qd * 8];
      short8 k1 = *(const short8*)&kls[(16 + ln) * 264 + ks * 32 + qd * 8];
      S0 = __builtin_amdgcn_mfma_f32_16x16x32_bf16(qf[ks], k0, S0, 0, 0, 0);
      S1 = __builtin_amdgcn_mfma_f32_16x16x32_bf16(qf[ks], k1, S1, 0, 0, 0);
    }
    float al[4];
#pragma unroll
    for (int r = 0; r < 4; ++r) {
      float sm = fmaxf(S0[r], S1[r]);
      sm = fmaxf(sm, __shfl_xor(sm, 1, 16));
      sm = fmaxf(sm, __shfl_xor(sm, 2, 16));
      sm = fmaxf(sm, __shfl_xor(sm, 4, 16));
      sm = fmaxf(sm, __shfl_xor(sm, 8, 16));
      float mn = fmaxf(m_run[r], sm);
      al[r] = __expf(m_run[r] - mn);
      float p0 = __expf(S0[r] - mn), p1 = __expf(S1[r] - mn);
      float rs = p0 + p1;
      rs += __shfl_xor(rs, 1, 16);
      rs += __shfl_xor(rs, 2, 16);
      rs += __shfl_xor(rs, 4, 16);
      rs += __shfl_xor(rs, 8, 16);
      l_run[r] = l_run[r] * al[r] + rs;
      m_run[r] = mn;
      pls[wv * 640 + (qd * 4 + r) * 40 + ln] = (short)to_bf(p0);
      pls[wv * 640 + (qd * 4 + r) * 40 + 16 + ln] = (short)to_bf(p1);
    }
#pragma unroll
    for (int cn = 0; cn < 16; ++cn) {
#pragma unroll
      for (int r = 0; r < 4; ++r) O[cn][r] *= al[r];
    }
    short8 pf = *(const short8*)&pls[wv * 640 + ln * 40 + qd * 8];
#pragma unroll
    for (int cn = 0; cn < 16; ++cn) {
      short8 vf = *(const short8*)&vls[(cn * 16 + ln) * 40 + qd * 8];
      O[cn] = __builtin_amdgcn_mfma_f32_16x16x32_bf16(pf, vf, O[cn], 0, 0, 0);
    }
    __syncthreads();
    if (t1 < 4096) {
#pragma unroll
      for (int i = 0; i < 4; ++i) {
        *(short8*)&kls[krow * 264 + (kch + i * 8) * 8] = kreg[i];
        *(short8*)&vls[(vcol + i * 64) * 40 + vch * 8] = vreg[i];
      }
    }
    __syncthreads();
  }
  float inv[4];
#pragma unroll
  for (int r = 0; r < 4; ++r) inv[r] = 1.f / l_run[r];
  float* op = oa + ((size_t)(b * 4096 + s0 + wv * 16 + qd * 4)) * 256 + ln;
#pragma unroll
  for (int cn = 0; cn < 16; ++cn) {
#pragma unroll
    for (int r = 0; r < 4; ++r)
      op[(size_t)r * 256 + cn * 16] = O[cn][r] * inv[r];
  }
}

// ---------- out projection + bias + residual; oa is [b][s][c] fp32
__global__ __launch_bounds__(256) void proj_k(const float* __restrict__ oa,
    const float* __restrict__ w, const float* __restrict__ ob,
    float* __restrict__ out) {
  __shared__ __align__(16) float wt[256 * 20];
  const int tid = threadIdx.x;
  const int s = blockIdx.x * 256 + tid;
  const int o0 = blockIdx.y * 16;
  const int b = blockIdx.z;
#pragma unroll
  for (int o = 0; o < 16; ++o) wt[tid * 20 + o] = w[(size_t)(o0 + o) * 256 + tid];
  __syncthreads();
  const float4* ip = (const float4*)(oa + ((size_t)(b * 4096) + s) * 256);
  float acc[16];
#pragma unroll
  for (int i = 0; i < 16; ++i) acc[i] = 0.f;
  for (int c4 = 0; c4 < 64; ++c4) {
    float4 nv = ip[c4];
    float xs[4] = {nv.x, nv.y, nv.z, nv.w};
#pragma unroll
    for (int cc = 0; cc < 4; ++cc) {
      const float4* wp = (const float4*)&wt[(c4 * 4 + cc) * 20];
      float wv[16];
      *(float4*)&wv[0]  = wp[0];
      *(float4*)&wv[4]  = wp[1];
      *(float4*)&wv[8]  = wp[2];
      *(float4*)&wv[12] = wp[3];
#pragma unroll
      for (int o = 0; o < 16; ++o) acc[o] = fmaf(wv[o], xs[cc], acc[o]);
    }
  }
#pragma unroll
  for (int o = 0; o < 16; ++o) {
    size_t idx = ((size_t)(b * 256 + o0 + o)) * 4096 + s;
    out[idx] = acc[o] + ob[o0 + o] + out[idx];
  }
}

extern "C" void kernel_launch(void* const* d_in, const int* in_sizes, int n_in,
                              void* d_out, int out_size, void* d_ws, size_t ws_size,
                              hipStream_t stream) {
  const float* x       = (const float*)d_in[0];
  const float* te      = (const float*)d_in[1];
  const float* gn1_s   = (const float*)d_in[2];
  const float* gn1_b   = (const float*)d_in[3];
  const float* conv1_w = (const float*)d_in[4];
  const float* conv1_b = (const float*)d_in[5];
  const float* mlp_w   = (const float*)d_in[6];
  const float* mlp_b   = (const float*)d_in[7];
  const float* gn2_s   = (const float*)d_in[8];
  const float* gn2_b   = (const float*)d_in[9];
  const float* conv2_w = (const float*)d_in[10];
  const float* conv2_b = (const float*)d_in[11];
  const float* gnA_s   = (const float*)d_in[12];
  const float* gnA_b   = (const float*)d_in[13];
  const float* qkv_w   = (const float*)d_in[14];
  const float* out_w   = (const float*)d_in[15];
  const float* out_b   = (const float*)d_in[16];
  float* out = (float*)d_out;

  float* bufA  = (float*)d_ws;       // gnA out / attn out (16MB)
  float* bufB  = bufA + NE;          // h1 fp32 [c][s] (16MB)
  short* qb    = (short*)(bufB + NE);// q bf16 / G conv-input bf16 (8MB)
  short* kb    = qb + NE;            // k bf16 / Wt1+Wt2 (8MB)
  short* vb    = kb + NE;            // v bf16 (8MB)
  float* stats = (float*)(vb + NE);  // 3 * 256 floats
  float* gbuf  = stats + 768;        // 2048 floats
  short* G     = qb;                 // alias: conv input, used before qkv
  short* Wt1   = kb;                 // alias: 9*256*256 shorts
  short* Wt2   = Wt1 + 589824;

  // --- weight prep (both convs) ---
  wprep_k<<<256, 256, 0, stream>>>(conv1_w, Wt1);
  wprep_k<<<256, 256, 0, stream>>>(conv2_w, Wt2);
  // --- ResNet block ---
  gn_stats_k<<<128, 256, 0, stream>>>(x, stats);
  film_k<<<8, 256, 0, stream>>>(te, mlp_w, mlp_b, gbuf);
  gn_silu_t_k<<<1024, 256, 0, stream>>>(x, stats, gn1_s, gn1_b, G);
  conv_mfma_k<0><<<256, 256, 0, stream>>>(G, Wt1, conv1_b, gbuf, nullptr, bufB);
  gn_stats_k<<<128, 256, 0, stream>>>(bufB, stats + 256);
  gn_silu_t_k<<<1024, 256, 0, stream>>>(bufB, stats + 256, gn2_s, gn2_b, G);
  conv_mfma_k<1><<<256, 256, 0, stream>>>(G, Wt2, conv2_b, nullptr, x, out);
  // --- Self-attention ---
  gn_stats_k<<<128, 256, 0, stream>>>(out, stats + 512);
  gn_apply_k<<<4096, 256, 0, stream>>>(out, stats + 512, gnA_s, gnA_b, bufA);
  qkv_k<<<dim3(16, 48, 4), 256, 0, stream>>>(bufA, qkv_w, qb, kb, vb);
  attn_k<<<dim3(64, 4), 256, 0, stream>>>(qb, kb, vb, bufA);
  proj_k<<<dim3(16, 16, 4), 256, 0, stream>>>(bufA, out_w, out_b, out);
}

// Round 4
// 617.953 us; speedup vs baseline: 5.5838x; 1.1196x over previous
//
#include <hip/hip_runtime.h>
#include <math.h>

#define SS 4096      // H*W
#define NE 4194304   // B*C*H*W

typedef __attribute__((ext_vector_type(8))) short short8;
typedef __attribute__((ext_vector_type(4))) short short4v;
typedef __attribute__((ext_vector_type(4))) float f32x4;
typedef __attribute__((ext_vector_type(16))) float f32x16;

__device__ __forceinline__ float wave_sum(float v) {
#pragma unroll
  for (int off = 32; off > 0; off >>= 1) v += __shfl_xor(v, off, 64);
  return v;
}
__device__ __forceinline__ float silu_f(float y) { return y / (1.f + __expf(-y)); }

__device__ __forceinline__ unsigned short to_bf(float x) {
  union { float f; unsigned u; } v; v.f = x;
  unsigned r = v.u + 0x7FFFu + ((v.u >> 16) & 1u);
  return (unsigned short)(r >> 16);
}
__device__ __forceinline__ float bf2f(short s) {
  union { unsigned u; float f; } v;
  v.u = ((unsigned)(unsigned short)s) << 16;
  return v.f;
}

// ---------- GroupNorm stats: one block per (b,group): 8 ch * 4096 contiguous floats
__global__ __launch_bounds__(256) void gn_stats_k(const float* __restrict__ x,
                                                  float* __restrict__ stats) {
  const float4* p = (const float4*)(x + (size_t)blockIdx.x * 32768);
  float s = 0.f, q = 0.f;
  for (int i = threadIdx.x; i < 8192; i += 256) {
    float4 v = p[i];
    s += v.x + v.y + v.z + v.w;
    q += v.x * v.x + v.y * v.y + v.z * v.z + v.w * v.w;
  }
  s = wave_sum(s); q = wave_sum(q);
  __shared__ float red[8];
  int wid = threadIdx.x >> 6;
  if ((threadIdx.x & 63) == 0) { red[wid] = s; red[wid + 4] = q; }
  __syncthreads();
  if (threadIdx.x == 0) {
    s = red[0] + red[1] + red[2] + red[3];
    q = red[4] + red[5] + red[6] + red[7];
    float m = s * (1.f / 32768.f);
    float var = q * (1.f / 32768.f) - m * m;
    stats[blockIdx.x * 2] = m;
    stats[blockIdx.x * 2 + 1] = rsqrtf(var + 1e-5f);
  }
}

// ---------- GN apply, fp32 out (attention path)
__global__ __launch_bounds__(256) void gn_apply_k(const float* __restrict__ x,
    const float* __restrict__ stats, const float* __restrict__ sc,
    const float* __restrict__ bi, float* __restrict__ out) {
  size_t i4 = ((size_t)blockIdx.x * 256 + threadIdx.x) * 4;
  int c = (int)((i4 >> 12) & 255);
  int b = (int)(i4 >> 20);
  int sidx = (b * 32 + (c >> 3)) * 2;
  float m = stats[sidx], r = stats[sidx + 1];
  float a = sc[c] * r;
  float t = bi[c] - m * a;
  float4 v = *(const float4*)(x + i4);
  float4 o;
  o.x = v.x * a + t; o.y = v.y * a + t; o.z = v.z * a + t; o.w = v.w * a + t;
  *(float4*)(out + i4) = o;
}

// ---------- fused GN + SiLU + bf16 + transpose -> G[b][s][c]  (conv input)
__global__ __launch_bounds__(256) void gn_silu_t_k(const float* __restrict__ x,
    const float* __restrict__ stats, const float* __restrict__ sc,
    const float* __restrict__ bi, short* __restrict__ G) {
  __shared__ short T[64][72];
  const int tid = threadIdx.x;
  const int st = blockIdx.x & 63;           // 64 s-tiles
  const int ct = (blockIdx.x >> 6) & 3;     // 4 c-tiles
  const int b = blockIdx.x >> 8;
  const int s0 = st * 64, c0 = ct * 64;
#pragma unroll
  for (int r = 0; r < 4; ++r) {
    int idx = r * 256 + tid;
    int c_l = idx >> 4, s4 = idx & 15;
    int c = c0 + c_l;
    int sidx = (b * 32 + (c >> 3)) * 2;
    float m = stats[sidx], rs = stats[sidx + 1];
    float a = sc[c] * rs;
    float t = bi[c] - m * a;
    float4 v = *(const float4*)(x + ((size_t)(b * 256 + c)) * 4096 + s0 + s4 * 4);
    T[s4 * 4 + 0][c_l] = (short)to_bf(silu_f(v.x * a + t));
    T[s4 * 4 + 1][c_l] = (short)to_bf(silu_f(v.y * a + t));
    T[s4 * 4 + 2][c_l] = (short)to_bf(silu_f(v.z * a + t));
    T[s4 * 4 + 3][c_l] = (short)to_bf(silu_f(v.w * a + t));
  }
  __syncthreads();
#pragma unroll
  for (int r = 0; r < 2; ++r) {
    int idx = r * 256 + tid;
    int s_l = idx >> 3, cg = idx & 7;
    *(short8*)(G + ((size_t)(b * 4096 + s0 + s_l)) * 256 + c0 + cg * 8) =
        *(const short8*)&T[s_l][cg * 8];
  }
}

// ---------- weight prep: W[oc][ic][3][3] fp32 -> Wt[t][oc][ic] bf16
__global__ __launch_bounds__(256) void wprep_k(const float* __restrict__ w,
                                               short* __restrict__ wt) {
  __shared__ short L[9][256];
  const int oc = blockIdx.x;
  const int tid = threadIdx.x;
  const float* wp = w + (size_t)oc * 2304;
  for (int i = tid; i < 2304; i += 256) {
    int ic = i / 9, t = i - ic * 9;
    L[t][ic] = (short)to_bf(wp[i]);
  }
  __syncthreads();
  for (int i = tid; i < 2304; i += 256) {
    int t = i >> 8, ic = i & 255;
    wt[((size_t)(t * 256 + oc)) * 256 + ic] = L[t][ic];
  }
}

__device__ __forceinline__ short8 ld2x4(const short* p) {
  short4v lo = *(const short4v*)p;
  short4v hi = *(const short4v*)(p + 4);
  short8 r;
  r[0] = lo[0]; r[1] = lo[1]; r[2] = lo[2]; r[3] = lo[3];
  r[4] = hi[0]; r[5] = hi[1]; r[6] = hi[2]; r[7] = hi[3];
  return r;
}

// ---------- MFMA 3x3 conv (9-tap implicit GEMM), bf16 in, fp32 out [b][c][s].
template <int MODE>
__global__ __launch_bounds__(256, 1) void conv_mfma_k(
    const short* __restrict__ G,     // [b][4096][256] bf16
    const short* __restrict__ Wt,    // [9][256][256] bf16
    const float* __restrict__ bias,
    const float* __restrict__ gb,    // FiLM [b][512]
    const float* __restrict__ resid,
    float* __restrict__ out) {
  __shared__ __align__(16) short Xs[6][66][36];
  __shared__ __align__(16) short Ws[9][64][32];
  const int tid = threadIdx.x;
  const int oc0 = (blockIdx.x & 3) * 64;
  const int oy = ((blockIdx.x >> 2) & 15) * 4;
  const int b = blockIdx.x >> 6;
  const int wv = tid >> 6, lane = tid & 63;
  const int ln = lane & 31, hf = lane >> 5;

  f32x16 O00 = {}, O01 = {}, O10 = {}, O11 = {};

  for (int ic0 = 0; ic0 < 256; ic0 += 32) {
    __syncthreads();
    for (int i = tid; i < 1584; i += 256) {
      int r = i / 264;
      int rem = i - r * 264;
      int col = rem >> 2, g = rem & 3;
      int gy = oy + r - 1, gx = col - 1;
      short4v lo = {0, 0, 0, 0}, hi = {0, 0, 0, 0};
      if ((unsigned)gy < 64u && (unsigned)gx < 64u) {
        const short* gp = G + ((size_t)(b * 4096 + gy * 64 + gx)) * 256 + ic0 + g * 8;
        lo = *(const short4v*)gp;
        hi = *(const short4v*)(gp + 4);
      }
      *(short4v*)&Xs[r][col][g * 8] = lo;
      *(short4v*)&Xs[r][col][g * 8 + 4] = hi;
    }
    for (int i = tid; i < 2304; i += 256) {
      int t = i >> 8;
      int rem = i & 255;
      int o = rem >> 2, g = rem & 3;
      *(short8*)&Ws[t][o][g * 8] =
          *(const short8*)(Wt + ((size_t)(t * 256 + oc0 + o)) * 256 + ic0 + g * 8);
    }
    __syncthreads();
    for (int t = 0; t < 9; ++t) {
      const int dy = t / 3, dx = t - dy * 3;
      const short* xrow = &Xs[wv + dy][0][0];
#pragma unroll
      for (int ks = 0; ks < 2; ++ks) {
        short8 a0 = *(const short8*)&Ws[t][ln][ks * 16 + hf * 8];
        short8 a1 = *(const short8*)&Ws[t][32 + ln][ks * 16 + hf * 8];
        short8 b0 = ld2x4(xrow + (ln + dx) * 36 + ks * 16 + hf * 8);
        short8 b1 = ld2x4(xrow + (32 + ln + dx) * 36 + ks * 16 + hf * 8);
        O00 = __builtin_amdgcn_mfma_f32_32x32x16_bf16(a0, b0, O00, 0, 0, 0);
        O01 = __builtin_amdgcn_mfma_f32_32x32x16_bf16(a0, b1, O01, 0, 0, 0);
        O10 = __builtin_amdgcn_mfma_f32_32x32x16_bf16(a1, b0, O10, 0, 0, 0);
        O11 = __builtin_amdgcn_mfma_f32_32x32x16_bf16(a1, b1, O11, 0, 0, 0);
      }
    }
  }
  const int srow = (oy + wv) * 64;
#pragma unroll
  for (int os = 0; os < 2; ++os) {
    const f32x16* Oa = os ? &O10 : &O00;
    const f32x16* Ob = os ? &O11 : &O01;
#pragma unroll
    for (int i = 0; i < 16; ++i) {
      int oc = oc0 + os * 32 + (i & 3) + 8 * (i >> 2) + 4 * hf;
      float bi = bias[oc];
      size_t base = ((size_t)(b * 256 + oc)) * 4096 + srow;
      float v0 = (*Oa)[i] + bi, v1 = (*Ob)[i] + bi;
      if (MODE == 0) {
        float ga = 1.f + gb[b * 512 + oc], be = gb[b * 512 + 256 + oc];
        v0 = ga * v0 + be;
        v1 = ga * v1 + be;
      } else {
        v0 += resid[base + ln];
        v1 += resid[base + 32 + ln];
      }
      out[base + ln] = v0;
      out[base + 32 + ln] = v1;
    }
  }
}

// ---------- FiLM MLP
__global__ __launch_bounds__(256) void film_k(const float* __restrict__ te,
    const float* __restrict__ w, const float* __restrict__ bi,
    float* __restrict__ gb) {
  int tid = blockIdx.x * 256 + threadIdx.x;  // 2048 threads
  int b = tid >> 9, j = tid & 511;
  const float* tp = te + b * 256;
  const float* wp = w + j * 256;
  float acc = bi[j];
  for (int t = 0; t < 256; ++t) acc += silu_f(tp[t]) * wp[t];
  gb[tid] = acc;
}

// ---------- 1x1 qkv GEMM: fp32 in, bf16 out in MFMA-friendly layouts.
__global__ __launch_bounds__(256) void qkv_k(const float* __restrict__ n,
    const float* __restrict__ wq, short* __restrict__ q, short* __restrict__ k,
    short* __restrict__ v) {
  __shared__ __align__(16) float wt[256 * 20];
  const int tid = threadIdx.x;
  const int s = blockIdx.x * 256 + tid;
  const int o0 = blockIdx.y * 16;
  const int b = blockIdx.z;
#pragma unroll
  for (int o = 0; o < 16; ++o) wt[tid * 20 + o] = wq[(size_t)(o0 + o) * 256 + tid];
  __syncthreads();
  const float* ip = n + (size_t)b * 256 * 4096 + s;
  float acc[16];
#pragma unroll
  for (int i = 0; i < 16; ++i) acc[i] = 0.f;
#pragma unroll 4
  for (int c = 0; c < 256; ++c) {
    float nv = ip[(size_t)c * 4096];
    const float4* wp = (const float4*)&wt[c * 20];
    float wv[16];
    *(float4*)&wv[0]  = wp[0];
    *(float4*)&wv[4]  = wp[1];
    *(float4*)&wv[8]  = wp[2];
    *(float4*)&wv[12] = wp[3];
#pragma unroll
    for (int o = 0; o < 16; ++o) acc[o] = fmaf(wv[o], nv, acc[o]);
  }
  if (o0 < 256) {
    union { short8 v8[2]; unsigned short s16[16]; } u;
#pragma unroll
    for (int o = 0; o < 16; ++o) u.s16[o] = to_bf(acc[o] * 0.0625f);
    short* qp = q + ((size_t)(b * 4096 + s)) * 256 + o0;
    *(short8*)qp = u.v8[0];
    *(short8*)(qp + 8) = u.v8[1];
  } else if (o0 < 512) {
    union { short8 v8[2]; unsigned short s16[16]; } u;
#pragma unroll
    for (int o = 0; o < 16; ++o) u.s16[o] = to_bf(acc[o]);
    short* kp = k + ((size_t)(b * 4096 + s)) * 256 + (o0 - 256);
    *(short8*)kp = u.v8[0];
    *(short8*)(kp + 8) = u.v8[1];
  } else {
#pragma unroll
    for (int o = 0; o < 16; ++o)
      v[((size_t)(b * 256 + o0 - 512 + o)) * 4096 + s] = (short)to_bf(acc[o]);
  }
}

// ---------- MFMA flash attention v2.
// q-tile 32, kv-split 4, 2048 blocks. Wave w owns keys w*16..w*16+15 of each
// 64-key tile (K A-frags DIRECT from global, prefetched) x all 32 queries
// (Q B-frags in registers). Common-m softmax via 1KB LDS exchange. PV:
// wave owns channels w*64..w*64+63; V through LDS (padded), P through LDS.
// Emits unnormalized bf16 partial O + (m,l) per kv-split; combined later.
__global__ __launch_bounds__(256, 2) void attn_k(const short* __restrict__ qb,
    const short* __restrict__ kb, const short* __restrict__ vb,
    short* __restrict__ part, float* __restrict__ ml) {
  __shared__ __align__(16) short vls[256 * 72];   // V tile [c][t] pad 72
  __shared__ __align__(16) short pls[32 * 72];    // P [q][t] pad 72
  __shared__ __align__(16) float mxs[32 * 4];     // per-wave max [q][w]
  __shared__ __align__(16) float lss[32 * 4];     // per-wave sum [q][w]
  const int tid = threadIdx.x;
  const int j = blockIdx.x & 7;           // XCD slot: batch b pinned to 2 XCDs
  const int b = j >> 1;
  const int idx = ((blockIdx.x >> 3) << 1) | (j & 1);  // 0..511
  const int z = idx >> 7;                 // kv split 0..3
  const int s0 = (idx & 127) * 32;        // q start within batch
  const int kv0 = z * 1024;
  const int w = tid >> 6, lane = tid & 63, ln = lane & 15, qd = lane >> 4;

  // Q B-frags in registers: qf[g][ks] : B[n=q=ln][k=ks*32+qd*8+j]
  short8 qf[2][8];
  {
    const short* qp = qb + ((size_t)(b * 4096 + s0 + ln)) * 256 + qd * 8;
#pragma unroll
    for (int g = 0; g < 2; ++g)
#pragma unroll
      for (int ks = 0; ks < 8; ++ks)
        qf[g][ks] = *(const short8*)(qp + g * 16 * 256 + ks * 32);
  }
  const f32x4 z4 = {0.f, 0.f, 0.f, 0.f};
  f32x4 O[2][4];  // [g][cs]: D[m=c][n=q], c = w*64+cs*16+qd*4+r
#pragma unroll
  for (int g = 0; g < 2; ++g)
#pragma unroll
    for (int cs = 0; cs < 4; ++cs) O[g][cs] = z4;
  float m_run[2] = {-3e38f, -3e38f}, l_run[2] = {0.f, 0.f};

  const short* kbb = kb + ((size_t)(b * 4096 + kv0)) * 256;
  const short* vbb = vb + ((size_t)b * 256) * 4096 + kv0;

  const int vr = tid >> 3;          // V staging: row base 0..31 (+p*32)
  const int vc = (tid & 7) * 8;     // t-chunk (shorts)

  short8 kreg[8], vreg[8];
#pragma unroll
  for (int ks = 0; ks < 8; ++ks)
    kreg[ks] = *(const short8*)(kbb + ((size_t)(w * 16 + ln)) * 256 + ks * 32 + qd * 8);
#pragma unroll
  for (int p = 0; p < 8; ++p)
    vreg[p] = *(const short8*)(vbb + ((size_t)(vr + p * 32)) * 4096 + vc);

  for (int t0 = 0; t0 < 1024; t0 += 64) {
    const int tn = (t0 + 64 < 1024) ? t0 + 64 : t0;
    __syncthreads();  // bar_C: prev PV done -> safe to overwrite vls/pls/mxs/lss
    // stage V tile t0
#pragma unroll
    for (int p = 0; p < 8; ++p)
      *(short8*)&vls[(vr + p * 32) * 72 + vc] = vreg[p];
    // prefetch next V
#pragma unroll
    for (int p = 0; p < 8; ++p)
      vreg[p] = *(const short8*)(vbb + ((size_t)(vr + p * 32)) * 4096 + tn + vc);
    // QK: S[g] = D[m=key(own 16)][n=q(g*16+ln)]
    f32x4 S[2] = {z4, z4};
#pragma unroll
    for (int ks = 0; ks < 8; ++ks) {
      S[0] = __builtin_amdgcn_mfma_f32_16x16x32_bf16(kreg[ks], qf[0][ks], S[0], 0, 0, 0);
      S[1] = __builtin_amdgcn_mfma_f32_16x16x32_bf16(kreg[ks], qf[1][ks], S[1], 0, 0, 0);
    }
    // prefetch next K
#pragma unroll
    for (int ks = 0; ks < 8; ++ks)
      kreg[ks] = *(const short8*)(kbb + ((size_t)(tn + w * 16 + ln)) * 256 + ks * 32 + qd * 8);
    // per-wave local max over own 16 keys (in-lane 4 + quad shuffles)
#pragma unroll
    for (int g = 0; g < 2; ++g) {
      float m0 = fmaxf(fmaxf(S[g][0], S[g][1]), fmaxf(S[g][2], S[g][3]));
      m0 = fmaxf(m0, __shfl_xor(m0, 16, 64));
      m0 = fmaxf(m0, __shfl_xor(m0, 32, 64));
      if (qd == 0) mxs[(g * 16 + ln) * 4 + w] = m0;
    }
    __syncthreads();  // bar_A
    float alf[2];
#pragma unroll
    for (int g = 0; g < 2; ++g) {
      const int q = g * 16 + ln;
      f32x4 mt4 = *(const f32x4*)&mxs[q * 4];
      float mt = fmaxf(fmaxf(mt4[0], mt4[1]), fmaxf(mt4[2], mt4[3]));
      float mn = fmaxf(m_run[g], mt);
      alf[g] = __expf(m_run[g] - mn);
      m_run[g] = mn;
      float p0 = __expf(S[g][0] - mn), p1 = __expf(S[g][1] - mn);
      float p2 = __expf(S[g][2] - mn), p3 = __expf(S[g][3] - mn);
      unsigned lo = (unsigned)to_bf(p0) | ((unsigned)to_bf(p1) << 16);
      unsigned hi = (unsigned)to_bf(p2) | ((unsigned)to_bf(p3) << 16);
      *(unsigned*)&pls[q * 72 + w * 16 + qd * 4] = lo;
      *(unsigned*)&pls[q * 72 + w * 16 + qd * 4 + 2] = hi;
      float lsv = (p0 + p1) + (p2 + p3);
      lsv += __shfl_xor(lsv, 16, 64);
      lsv += __shfl_xor(lsv, 32, 64);
      if (qd == 0) lss[q * 4 + w] = lsv;
      // rescale O by alpha
#pragma unroll
      for (int cs = 0; cs < 4; ++cs) O[g][cs] *= alf[g];
    }
    __syncthreads();  // bar_B
#pragma unroll
    for (int g = 0; g < 2; ++g) {
      f32x4 lt4 = *(const f32x4*)&lss[(g * 16 + ln) * 4];
      l_run[g] = l_run[g] * alf[g] + ((lt4[0] + lt4[1]) + (lt4[2] + lt4[3]));
    }
    // PV: O[g][cs] += V[c][t] * P[q][t]
#pragma unroll
    for (int kc = 0; kc < 2; ++kc) {
      short8 pf0 = *(const short8*)&pls[ln * 72 + kc * 32 + qd * 8];
      short8 pf1 = *(const short8*)&pls[(16 + ln) * 72 + kc * 32 + qd * 8];
#pragma unroll
      for (int cs = 0; cs < 4; ++cs) {
        short8 vf = *(const short8*)&vls[(w * 64 + cs * 16 + ln) * 72 + kc * 32 + qd * 8];
        O[0][cs] = __builtin_amdgcn_mfma_f32_16x16x32_bf16(vf, pf0, O[0][cs], 0, 0, 0);
        O[1][cs] = __builtin_amdgcn_mfma_f32_16x16x32_bf16(vf, pf1, O[1][cs], 0, 0, 0);
      }
    }
  }
  // epilogue: store bf16 partial O (unnormalized) + (m,l)
  const size_t prow = (size_t)z * 16384 + (size_t)b * 4096 + s0;
#pragma unroll
  for (int g = 0; g < 2; ++g) {
    short* pp = part + (prow + g * 16 + ln) * 256 + w * 64 + qd * 4;
#pragma unroll
    for (int cs = 0; cs < 4; ++cs) {
      short4v o4;
      o4[0] = (short)to_bf(O[g][cs][0]);
      o4[1] = (short)to_bf(O[g][cs][1]);
      o4[2] = (short)to_bf(O[g][cs][2]);
      o4[3] = (short)to_bf(O[g][cs][3]);
      *(short4v*)(pp + cs * 16) = o4;
    }
    if (w == 0 && qd == 0) {
      float2 v2;
      v2.x = m_run[g];
      v2.y = l_run[g];
      *(float2*)(ml + (prow + g * 16 + ln) * 2) = v2;
    }
  }
}

// ---------- combine kv-split partials -> bf16 oa [b*s][c] (in place over part[0])
__global__ __launch_bounds__(256) void attn_comb_k(const short* __restrict__ part,
    const float* __restrict__ ml, short* __restrict__ oa) {
  const int row = blockIdx.x * 4 + (threadIdx.x >> 6);
  const int c0 = (threadIdx.x & 63) * 4;
  float mz[4], lz[4];
#pragma unroll
  for (int z = 0; z < 4; ++z) {
    const float* mp = ml + ((size_t)z * 16384 + row) * 2;
    mz[z] = mp[0];
    lz[z] = mp[1];
  }
  float M = fmaxf(fmaxf(mz[0], mz[1]), fmaxf(mz[2], mz[3]));
  float wz[4], den = 0.f;
#pragma unroll
  for (int z = 0; z < 4; ++z) {
    wz[z] = __expf(mz[z] - M);
    den += lz[z] * wz[z];
  }
  float inv = 1.f / den;
  float acc[4] = {0.f, 0.f, 0.f, 0.f};
#pragma unroll
  for (int z = 0; z < 4; ++z) {
    short4v p4 = *(const short4v*)(part + ((size_t)z * 16384 + row) * 256 + c0);
#pragma unroll
    for (int r = 0; r < 4; ++r) acc[r] += bf2f(p4[r]) * wz[z];
  }
  short4v o;
#pragma unroll
  for (int r = 0; r < 4; ++r) o[r] = (short)to_bf(acc[r] * inv);
  *(short4v*)(oa + (size_t)row * 256 + c0) = o;
}

// ---------- out projection + bias + residual; oa is [b][s][c] bf16
__global__ __launch_bounds__(256) void proj_k(const short* __restrict__ oa,
    const float* __restrict__ w, const float* __restrict__ ob,
    float* __restrict__ out) {
  __shared__ __align__(16) float wt[256 * 20];
  const int tid = threadIdx.x;
  const int s = blockIdx.x * 256 + tid;
  const int o0 = blockIdx.y * 16;
  const int b = blockIdx.z;
#pragma unroll
  for (int o = 0; o < 16; ++o) wt[tid * 20 + o] = w[(size_t)(o0 + o) * 256 + tid];
  __syncthreads();
  const short4v* ip = (const short4v*)(oa + ((size_t)(b * 4096) + s) * 256);
  float acc[16];
#pragma unroll
  for (int i = 0; i < 16; ++i) acc[i] = 0.f;
  for (int c4 = 0; c4 < 64; ++c4) {
    short4v nv = ip[c4];
    float xs[4] = {bf2f(nv[0]), bf2f(nv[1]), bf2f(nv[2]), bf2f(nv[3])};
#pragma unroll
    for (int cc = 0; cc < 4; ++cc) {
      const float4* wp = (const float4*)&wt[(c4 * 4 + cc) * 20];
      float wv[16];
      *(float4*)&wv[0]  = wp[0];
      *(float4*)&wv[4]  = wp[1];
      *(float4*)&wv[8]  = wp[2];
      *(float4*)&wv[12] = wp[3];
#pragma unroll
      for (int o = 0; o < 16; ++o) acc[o] = fmaf(wv[o], xs[cc], acc[o]);
    }
  }
#pragma unroll
  for (int o = 0; o < 16; ++o) {
    size_t idx = ((size_t)(b * 256 + o0 + o)) * 4096 + s;
    out[idx] = acc[o] + ob[o0 + o] + out[idx];
  }
}

extern "C" void kernel_launch(void* const* d_in, const int* in_sizes, int n_in,
                              void* d_out, int out_size, void* d_ws, size_t ws_size,
                              hipStream_t stream) {
  const float* x       = (const float*)d_in[0];
  const float* te      = (const float*)d_in[1];
  const float* gn1_s   = (const float*)d_in[2];
  const float* gn1_b   = (const float*)d_in[3];
  const float* conv1_w = (const float*)d_in[4];
  const float* conv1_b = (const float*)d_in[5];
  const float* mlp_w   = (const float*)d_in[6];
  const float* mlp_b   = (const float*)d_in[7];
  const float* gn2_s   = (const float*)d_in[8];
  const float* gn2_b   = (const float*)d_in[9];
  const float* conv2_w = (const float*)d_in[10];
  const float* conv2_b = (const float*)d_in[11];
  const float* gnA_s   = (const float*)d_in[12];
  const float* gnA_b   = (const float*)d_in[13];
  const float* qkv_w   = (const float*)d_in[14];
  const float* out_w   = (const float*)d_in[15];
  const float* out_b   = (const float*)d_in[16];
  float* out = (float*)d_out;

  float* bufA  = (float*)d_ws;       // gnA out fp32 (16MB); later attn partials
  float* bufB  = bufA + NE;          // h1 fp32 [c][s] (16MB); later attn partials
  short* qb    = (short*)(bufB + NE);// q bf16 / G conv-input bf16 (8MB)
  short* kb    = qb + NE;            // k bf16 / Wt1+Wt2 (8MB)
  short* vb    = kb + NE;            // v bf16 (8MB)
  float* mlb   = (float*)(vb + NE);  // attn (m,l): 4*16384*2 floats (512KB)
  float* stats = mlb + 131072;       // 3 * 256 floats
  float* gbuf  = stats + 768;        // 2048 floats
  short* G     = qb;                 // alias: conv input
  short* Wt1   = kb;                 // alias: 9*256*256 shorts
  short* Wt2   = Wt1 + 589824;
  short* partb = (short*)bufA;       // attn partials bf16 [4][16384][256] (32MB)

  // --- weight prep (both convs) ---
  wprep_k<<<256, 256, 0, stream>>>(conv1_w, Wt1);
  wprep_k<<<256, 256, 0, stream>>>(conv2_w, Wt2);
  // --- ResNet block ---
  gn_stats_k<<<128, 256, 0, stream>>>(x, stats);
  film_k<<<8, 256, 0, stream>>>(te, mlp_w, mlp_b, gbuf);
  gn_silu_t_k<<<1024, 256, 0, stream>>>(x, stats, gn1_s, gn1_b, G);
  conv_mfma_k<0><<<256, 256, 0, stream>>>(G, Wt1, conv1_b, gbuf, nullptr, bufB);
  gn_stats_k<<<128, 256, 0, stream>>>(bufB, stats + 256);
  gn_silu_t_k<<<1024, 256, 0, stream>>>(bufB, stats + 256, gn2_s, gn2_b, G);
  conv_mfma_k<1><<<256, 256, 0, stream>>>(G, Wt2, conv2_b, nullptr, x, out);
  // --- Self-attention ---
  gn_stats_k<<<128, 256, 0, stream>>>(out, stats + 512);
  gn_apply_k<<<4096, 256, 0, stream>>>(out, stats + 512, gnA_s, gnA_b, bufA);
  qkv_k<<<dim3(16, 48, 4), 256, 0, stream>>>(bufA, qkv_w, qb, kb, vb);
  attn_k<<<2048, 256, 0, stream>>>(qb, kb, vb, partb, mlb);
  attn_comb_k<<<4096, 256, 0, stream>>>(partb, mlb, partb);
  proj_k<<<dim3(16, 16, 4), 256, 0, stream>>>(partb, out_w, out_b, out);
}